// Round 6
// baseline (80.587 us; speedup 1.0000x reference)
//
#include <hip/hip_runtime.h>

// Problem constants: logits (N=4, C=19, H=512, W=1024) float32; target unused.
#define NCLS 19
#define NSMP 4
#define HW   (512 * 1024)
#define NSEG (NSMP * NCLS)   // 76 segments

// ws layout (floats): [0..76) = S1, [76..152) = S2, [152..228) = cnt
//
// R6 probe: stage reads through the async global->LDS DMA path
// (__builtin_amdgcn_global_load_lds, width=16) instead of vector loads,
// to test whether the ~3.3 TB/s read ceiling is the VGPR-return miss
// tracker (DMA path separate -> win) or shared (flat -> roofline).
//
// 4096 blocks x 256 threads; block covers 512 contiguous pixels of one
// sample (524288 % 512 == 0). LDS: ch[19][512] floats = 38 KB -> 4 blocks/CU.
// Staging: 38 chunks of 1 KB (channel c, half h); wave w takes chunks
// j = w, w+4, ... Each instr: lane l supplies gptr, data lands at
// ldsbase + l*16 (linear, matches layout). Compute: thread t handles
// pixels {t, t+256}; ds_read_b32 lanes contiguous -> conflict-free.
__global__ __launch_bounds__(256) void cl_main(const float* __restrict__ logits,
                                               float* __restrict__ ws) {
    __shared__ float ch[NCLS * 512];   // [c][512], halves of 256 floats
    __shared__ float sb[3 * NCLS];     // [S1_19 | S2_19 | cnt_19]
    const int tid = threadIdx.x;
    if (tid < 3 * NCLS) sb[tid] = 0.0f;

    const int    n    = blockIdx.x >> 10;                    // 1024 blocks per sample
    const size_t off  = (size_t)(blockIdx.x & 1023) * 512;   // pixel offset in sample
    const float* base = logits + (size_t)n * NCLS * HW + off;

    const int w = tid >> 6;      // wave id (uniform per wave)
    const int l = tid & 63;      // lane

    for (int j = w; j < 2 * NCLS; j += 4) {
        const int c = j >> 1;
        const int h = j & 1;
        const float* g = base + (size_t)c * HW + h * 256 + l * 4;
        __builtin_amdgcn_global_load_lds(
            (const __attribute__((address_space(1))) void*)g,
            (__attribute__((address_space(3))) void*)&ch[j * 256],
            16, 0, 0);
    }
    __syncthreads();   // drains vmcnt (global_load_lds) + lds init visible

    float s1[2], s2[2], mv[2];
    int   mi[2];
    #pragma unroll
    for (int k = 0; k < 2; ++k) {
        const int p = tid + (k << 8);
        const float a0 = ch[p];          // c = 0
        s1[k] = a0; s2[k] = a0 * a0; mv[k] = a0; mi[k] = 0;
        #pragma unroll
        for (int c = 1; c < NCLS; ++c) {
            const float a = ch[c * 512 + p];
            s1[k] += a;
            s2[k]  = fmaf(a, a, s2[k]);
            if (a > mv[k]) { mv[k] = a; mi[k] = c; }  // strict > = first-index argmax
        }
    }

    #pragma unroll
    for (int k = 0; k < 2; ++k) {
        atomicAdd(&sb[mi[k]],      s1[k]);
        atomicAdd(&sb[19 + mi[k]], s2[k]);
        atomicAdd(&sb[38 + mi[k]], 1.0f);
    }
    __syncthreads();

    if (tid < NCLS) {
        const int seg = n * NCLS + tid;
        atomicAdd(&ws[seg],            sb[tid]);
        atomicAdd(&ws[NSEG + seg],     sb[19 + tid]);
        atomicAdd(&ws[2 * NSEG + seg], sb[38 + tid]);
    }
}

__global__ void cl_final(const float* __restrict__ ws, float* __restrict__ out) {
    __shared__ float red[128];
    const int i = threadIdx.x;
    float v = 0.0f;
    if (i < NSEG) {
        const float S1  = ws[i];
        const float S2  = ws[NSEG + i];
        const float cnt = ws[2 * NSEG + i];
        const float K   = fmaxf(cnt, 1.0f) * (float)NCLS;
        const float sq  = fmaxf(S2 - S1 * S1 / K, 0.0f);
        v = (cnt > 0.0f) ? sqrtf(sq) : 0.0f;
    }
    red[i] = v;
    __syncthreads();
    #pragma unroll
    for (int s = 64; s > 0; s >>= 1) {
        if (i < s) red[i] += red[i + s];
        __syncthreads();
    }
    if (i == 0) out[0] = red[0] / (float)NSMP;
}

extern "C" void kernel_launch(void* const* d_in, const int* in_sizes, int n_in,
                              void* d_out, int out_size, void* d_ws, size_t ws_size,
                              hipStream_t stream) {
    const float* logits = (const float*)d_in[0];
    // d_in[1] (target) is unused by the reference computation.
    float* ws  = (float*)d_ws;
    float* out = (float*)d_out;

    hipMemsetAsync(ws, 0, 3 * NSEG * sizeof(float), stream);
    cl_main<<<4096, 256, 0, stream>>>(logits, ws);
    cl_final<<<1, 128, 0, stream>>>(ws, out);
}

// Round 7
// 54.655 us; speedup vs baseline: 1.4745x; 1.4745x over previous
//
#include <hip/hip_runtime.h>

// Problem constants: logits (N=4, C=19, H=512, W=1024) float32; target unused.
#define NCLS 19
#define NSMP 4
#define HW   (512 * 1024)
#define NSEG (NSMP * NCLS)   // 76 segments

// ws layout (floats): [0..76) = S1, [76..152) = S2, [152..228) = cnt
//
// R7 probe (TLB/page-locality): 512 blocks x 256 threads x 16 px/thread,
// processed as 4 sequential rounds of the proven R2 body. Block covers
// 4096 CONTIGUOUS pixels of one sample -> its 19 channel chunks (16 KB each)
// live on the same 19 pages for the whole block lifetime; 2 blocks/CU ->
// ~38 live translations/CU (vs ~150 in R2). If the ~3.3 TB/s read ceiling
// is translation-latency-limited, this rises; if flat, it's a hard read cap.
__global__ __launch_bounds__(256) void cl_main(const float* __restrict__ logits,
                                               float* __restrict__ ws) {
    __shared__ float sb[3 * NCLS];   // [S1_19 | S2_19 | cnt_19]
    const int tid = threadIdx.x;
    if (tid < 3 * NCLS) sb[tid] = 0.0f;
    __syncthreads();

    const int    n    = blockIdx.x >> 7;                      // 128 blocks per sample
    const size_t bpix = (size_t)(blockIdx.x & 127) * 4096;    // block pixel offset
    const float* base = logits + (size_t)n * NCLS * HW + bpix + (size_t)tid * 4;

    #pragma unroll
    for (int r = 0; r < 4; ++r) {
        // ---- batch all 19 channel loads for this round ----
        float4 v[NCLS];
        #pragma unroll
        for (int c = 0; c < NCLS; ++c) {
            v[c] = *(const float4*)(base + (size_t)c * HW + (size_t)r * 1024);
        }
        asm volatile("" ::: "memory");

        float s1[4], s2[4], mv[4];
        int   mi[4];
        {
            const float a0[4] = {v[0].x, v[0].y, v[0].z, v[0].w};
            #pragma unroll
            for (int j = 0; j < 4; ++j) {
                s1[j] = a0[j];
                s2[j] = a0[j] * a0[j];
                mv[j] = a0[j];
                mi[j] = 0;
            }
        }
        #pragma unroll
        for (int c = 1; c < NCLS; ++c) {
            const float a[4] = {v[c].x, v[c].y, v[c].z, v[c].w};
            #pragma unroll
            for (int j = 0; j < 4; ++j) {
                s1[j] += a[j];
                s2[j]  = fmaf(a[j], a[j], s2[j]);
                if (a[j] > mv[j]) { mv[j] = a[j]; mi[j] = c; }  // strict > = first-idx argmax
            }
        }

        #pragma unroll
        for (int j = 0; j < 4; ++j) {
            atomicAdd(&sb[mi[j]],      s1[j]);
            atomicAdd(&sb[19 + mi[j]], s2[j]);
            atomicAdd(&sb[38 + mi[j]], 1.0f);
        }
        asm volatile("" ::: "memory");
    }
    __syncthreads();

    if (tid < NCLS) {
        const int seg = n * NCLS + tid;
        atomicAdd(&ws[seg],            sb[tid]);
        atomicAdd(&ws[NSEG + seg],     sb[19 + tid]);
        atomicAdd(&ws[2 * NSEG + seg], sb[38 + tid]);
    }
}

__global__ void cl_final(const float* __restrict__ ws, float* __restrict__ out) {
    __shared__ float red[128];
    const int i = threadIdx.x;
    float v = 0.0f;
    if (i < NSEG) {
        const float S1  = ws[i];
        const float S2  = ws[NSEG + i];
        const float cnt = ws[2 * NSEG + i];
        const float K   = fmaxf(cnt, 1.0f) * (float)NCLS;
        const float sq  = fmaxf(S2 - S1 * S1 / K, 0.0f);
        v = (cnt > 0.0f) ? sqrtf(sq) : 0.0f;
    }
    red[i] = v;
    __syncthreads();
    #pragma unroll
    for (int s = 64; s > 0; s >>= 1) {
        if (i < s) red[i] += red[i + s];
        __syncthreads();
    }
    if (i == 0) out[0] = red[0] / (float)NSMP;
}

extern "C" void kernel_launch(void* const* d_in, const int* in_sizes, int n_in,
                              void* d_out, int out_size, void* d_ws, size_t ws_size,
                              hipStream_t stream) {
    const float* logits = (const float*)d_in[0];
    // d_in[1] (target) is unused by the reference computation.
    float* ws  = (float*)d_ws;
    float* out = (float*)d_out;

    hipMemsetAsync(ws, 0, 3 * NSEG * sizeof(float), stream);
    cl_main<<<512, 256, 0, stream>>>(logits, ws);
    cl_final<<<1, 128, 0, stream>>>(ws, out);
}